// Round 10
// baseline (82.007 us; speedup 1.0000x reference)
//
#include <hip/hip_runtime.h>
#include <hip/hip_fp16.h>
#include <math.h>

#define BATCH 8
#define NSLOT 256
#define DDIM  256
#define HID   128
#define NREL  8

typedef _Float16 half8 __attribute__((ext_vector_type(8)));
typedef float float4v __attribute__((ext_vector_type(4)));

union U8 {
  uint32_t u[4];
  _Float16 f[8];
  half8 v;
  float4 f4;
};

union U4 {
  uint32_t u[2];
  _Float16 f[4];
  uint2 u2;
};

// ---------------------------------------------------------------------------
// R23: INSTRUMENTATION round — direct sizing of proj via idempotent
// duplication (mirror of R19 which sized pair at ~9.5us). R20/R21/R22
// falsified every structural theory of "proj ~= 24us" (access patterns,
// cache state, TLP/chain depth — all null at 78.1-78.9), leaving two
// competing models with OPPOSITE predictions for a duplicated proj:
//  (a) proj intrinsic ~24us -> dur ~100-106;
//  (b) window is poison-BW-dominated (2x256MiB fills ~= 512MiB at ~6.7TB/s
//      ~= 78us) and proj is actually ~2us -> dur ~79-82 -> we are AT the
//      harness floor -> declare roofline next round.
// Base = R20 exact (session best 78.08). Second proj re-reads L2-warm
// slots/W1 and rewrites identical P values (1MB, L2) -> ~zero BW cost; the
// delta is proj_warm_exec + ~1us dispatch overhead, cleanly.
// d_ws: P f16[2048][256] at 0 (1 MB).
//
// MFMA maps (HW-validated R5-R12): A[m=lane&15][k=(lane>>4)*8+u],
//  B[k=(lane>>4)*8+u][n=lane&15], D[m=(lane>>4)*4+reg][n=lane&15].
// ---------------------------------------------------------------------------

// proj (byte-identical to R20): P[r][c] = dot(slots[r], concatW[:,c]) + bias
//   concatW[k][c] = (c<128) ? W1[k][c] : W1[256+k][c-128]
__global__ __launch_bounds__(256) void proj_kernel(
    const float* __restrict__ slots, const float* __restrict__ W1,
    const float* __restrict__ b1, _Float16* __restrict__ P) {
  __shared__ _Float16 SL[16 * 264];  // 16 rows x (256 + 8 pad) f16

  const int tid  = threadIdx.x;
  const int w    = tid >> 6;
  const int lane = tid & 63;
  const int lo16 = lane & 15;
  const int kg   = lane >> 4;
  const int row0 = blockIdx.y * 16;
  const int c    = (blockIdx.x * 4 + w) * 16 + lo16;

  // coalesced slot-tile loads (1KB contiguous per wave-load)
  float4 sv[4];
  {
    const float* gbase = slots + (size_t)row0 * DDIM;
#pragma unroll
    for (int p = 0; p < 4; ++p) {
      const int idx = p * 256 + tid;
      sv[p] = *(const float4*)(gbase + (idx >> 6) * DDIM + (idx & 63) * 4);
    }
  }

  // W B-frags (strided dwords, L2-resident)
  const float* Wcol =
      (c < HID) ? (W1 + c) : (W1 + (size_t)DDIM * HID + (c - HID));
  U8 bf[8];
#pragma unroll
  for (int ks = 0; ks < 8; ++ks) {
    const int kb = ks * 32 + kg * 8;
#pragma unroll
    for (int u = 0; u < 8; ++u)
      bf[ks].f[u] = (_Float16)Wcol[(size_t)(kb + u) * HID];
  }

  // cvt + LDS write (b64, conflict-free)
#pragma unroll
  for (int p = 0; p < 4; ++p) {
    const int idx = p * 256 + tid;
    U4 h;
    h.f[0] = (_Float16)sv[p].x; h.f[1] = (_Float16)sv[p].y;
    h.f[2] = (_Float16)sv[p].z; h.f[3] = (_Float16)sv[p].w;
    *(uint2*)&SL[(idx >> 6) * 264 + (idx & 63) * 4] = h.u2;
  }

  __syncthreads();

  float4v acc = {0.0f, 0.0f, 0.0f, 0.0f};
#pragma unroll
  for (int ks = 0; ks < 8; ++ks) {
    U8 a;
    a.f4 = *(const float4*)&SL[lo16 * 264 + ks * 32 + kg * 8];
    acc = __builtin_amdgcn_mfma_f32_16x16x32_f16(a.v, bf[ks].v, acc, 0, 0, 0);
  }

  const float bias = (c < HID) ? b1[c] : 0.0f;
#pragma unroll
  for (int reg = 0; reg < 4; ++reg)
    P[(size_t)(row0 + kg * 4 + reg) * 256 + c] = (_Float16)(acc[reg] + bias);
}

// pair (byte-identical to R14/R19/R20/R21/R22 session-best config)
// out[b,i,j,r] = sigmoid( sum_k relu(P[b,i,k]+P[b,j,128+k]) * W2[k,r] + b2[r] )
__global__ __launch_bounds__(256) void pair_kernel(
    const _Float16* __restrict__ P, const float* __restrict__ W2,
    const float* __restrict__ b2, float* __restrict__ out) {
  __shared__ uint32_t PiL[8 * 68];

  const int tid  = threadIdx.x;
  const int w    = tid >> 6;
  const int lane = tid & 63;
  const int n    = lane & 15;
  const int kg   = lane >> 4;

  const int b  = blockIdx.z;
  const int i0 = blockIdx.y * 8;
  const int j0 = blockIdx.x * 64 + w * 16;
  const _Float16* Pb = P + (size_t)b * NSLOT * 256;

  if (tid < 128) {  // stage Pi: 8 rows x 128 f16
    const int r  = tid >> 4;
    const int ch = tid & 15;
    const float4 t = *(const float4*)(Pb + (size_t)(i0 + r) * 256 + ch * 8);
    *(float4*)&PiL[r * 68 + ch * 4] = t;
  }

  U8 w2f[4];
#pragma unroll
  for (int kq = 0; kq < 4; ++kq) {
    const int kb = kq * 32 + kg * 8;
#pragma unroll
    for (int u = 0; u < 8; ++u) {
      const float v = W2[(kb + u) * NREL + (n & 7)];  // 4KB, L1-resident
      w2f[kq].f[u] = (n < NREL) ? (_Float16)v : (_Float16)0.0f;
    }
  }

  const float b2v = (n < NREL) ? b2[n & 7] : 0.0f;

  U8 pj[4];
#pragma unroll
  for (int kq = 0; kq < 4; ++kq)
    pj[kq].f4 =
        *(const float4*)(Pb + (size_t)(j0 + n) * 256 + HID + kq * 32 + kg * 8);

  __syncthreads();

#pragma unroll
  for (int i = 0; i < 8; ++i) {
    float4v acc = {0.0f, 0.0f, 0.0f, 0.0f};
#pragma unroll
    for (int kq = 0; kq < 4; ++kq) {
      U8 pi;
      pi.f4 = *(const float4*)&PiL[i * 68 + kq * 16 + kg * 4];  // broadcast
      U8 h;
      h.v = __builtin_elementwise_max(pj[kq].v + pi.v, (half8)(_Float16)0.0f);
      acc = __builtin_amdgcn_mfma_f32_16x16x32_f16(h.v, w2f[kq].v, acc, 0, 0, 0);
    }
    if (n < NREL) {
      float* obase =
          out + (((size_t)b * NSLOT + (i0 + i)) * NSLOT + j0) * NREL + n;
#pragma unroll
      for (int reg = 0; reg < 4; ++reg) {
        const int jrow = kg * 4 + reg;
        const float x = acc[reg] + b2v;
        obase[jrow * NREL] = __builtin_amdgcn_rcpf(1.0f + __expf(-x));
      }
    }
  }
}

extern "C" void kernel_launch(void* const* d_in, const int* in_sizes, int n_in,
                              void* d_out, int out_size, void* d_ws,
                              size_t ws_size, hipStream_t stream) {
  const float* slots = (const float*)d_in[0];  // [8,256,256]
  const float* W1    = (const float*)d_in[1];  // [512,128]
  const float* b1    = (const float*)d_in[2];  // [128]
  const float* W2    = (const float*)d_in[3];  // [128,8]
  const float* b2    = (const float*)d_in[4];  // [8]
  float* out  = (float*)d_out;                 // [8,256,256,8]
  _Float16* P = (_Float16*)d_ws;               // 1 MB

  proj_kernel<<<dim3(4, 128), 256, 0, stream>>>(slots, W1, b1, P);
  // R23 instrumentation: duplicated idempotent dispatch. dur_us delta vs the
  // 78.08us R20 baseline ~= proj_warm_exec + ~1us dispatch overhead.
  proj_kernel<<<dim3(4, 128), 256, 0, stream>>>(slots, W1, b1, P);
  pair_kernel<<<dim3(NSLOT / 64, NSLOT / 8, BATCH), 256, 0, stream>>>(P, W2,
                                                                      b2, out);
}

// Round 11
// 78.587 us; speedup vs baseline: 1.0435x; 1.0435x over previous
//
#include <hip/hip_runtime.h>
#include <hip/hip_fp16.h>
#include <math.h>

#define BATCH 8
#define NSLOT 256
#define DDIM  256
#define HID   128
#define NREL  8

typedef _Float16 half8 __attribute__((ext_vector_type(8)));
typedef float float4v __attribute__((ext_vector_type(4)));

union U8 {
  uint32_t u[4];
  _Float16 f[8];
  half8 v;
  float4 f4;
};

union U4 {
  uint32_t u[2];
  _Float16 f[4];
  uint2 u2;
};

// ---------------------------------------------------------------------------
// R24: single-variable W2T test on pair. R23 killed "proj=24us" (dup-proj =
// +3.9 -> proj_warm ~3us). Consistent model: chain serial+exposed (R19/R21/
// R23 increments ~1:1), fills_exposed ~63.5us (harness-fixed), controllable
// budget ~14.5us of which pair ~9.5 (3.5x its 2.7us write-BW floor). pair's
// fattest prologue item: 32 scalar W2 dwords + 32 cvt per thread. Replace
// with 4x float4 from precomputed f16 W2T[16][128] (R0-validated build in
// proj block(0,0); R18 bundled this with the IT=4 regression — never
// isolated). Everything else byte-identical to R20 (78.08 session best).
// d_ws: P f16[2048][256] at 0 (1 MB); W2T f16[16][128] at 1 MB.
//
// MFMA maps (HW-validated R5-R12): A[m=lane&15][k=(lane>>4)*8+u],
//  B[k=(lane>>4)*8+u][n=lane&15], D[m=(lane>>4)*4+reg][n=lane&15].
// ---------------------------------------------------------------------------

// proj (R20-identical body): P[r][c] = dot(slots[r], concatW[:,c]) + bias
//   concatW[k][c] = (c<128) ? W1[k][c] : W1[256+k][c-128]
// Block (0,0) additionally builds W2T[n][k] = (f16)W2[k][n] (zero for n>=8).
__global__ __launch_bounds__(256) void proj_kernel(
    const float* __restrict__ slots, const float* __restrict__ W1,
    const float* __restrict__ b1, const float* __restrict__ W2,
    _Float16* __restrict__ P, _Float16* __restrict__ W2T) {
  __shared__ _Float16 SL[16 * 264];  // 16 rows x (256 + 8 pad) f16

  const int tid  = threadIdx.x;
  const int w    = tid >> 6;
  const int lane = tid & 63;
  const int lo16 = lane & 15;
  const int kg   = lane >> 4;
  const int row0 = blockIdx.y * 16;
  const int c    = (blockIdx.x * 4 + w) * 16 + lo16;

  // coalesced slot-tile loads (1KB contiguous per wave-load)
  float4 sv[4];
  {
    const float* gbase = slots + (size_t)row0 * DDIM;
#pragma unroll
    for (int p = 0; p < 4; ++p) {
      const int idx = p * 256 + tid;
      sv[p] = *(const float4*)(gbase + (idx >> 6) * DDIM + (idx & 63) * 4);
    }
  }

  // W B-frags (strided dwords, L2-resident)
  const float* Wcol =
      (c < HID) ? (W1 + c) : (W1 + (size_t)DDIM * HID + (c - HID));
  U8 bf[8];
#pragma unroll
  for (int ks = 0; ks < 8; ++ks) {
    const int kb = ks * 32 + kg * 8;
#pragma unroll
    for (int u = 0; u < 8; ++u)
      bf[ks].f[u] = (_Float16)Wcol[(size_t)(kb + u) * HID];
  }

  // cvt + LDS write (b64, conflict-free)
#pragma unroll
  for (int p = 0; p < 4; ++p) {
    const int idx = p * 256 + tid;
    U4 h;
    h.f[0] = (_Float16)sv[p].x; h.f[1] = (_Float16)sv[p].y;
    h.f[2] = (_Float16)sv[p].z; h.f[3] = (_Float16)sv[p].w;
    *(uint2*)&SL[(idx >> 6) * 264 + (idx & 63) * 4] = h.u2;
  }

  __syncthreads();

  float4v acc = {0.0f, 0.0f, 0.0f, 0.0f};
#pragma unroll
  for (int ks = 0; ks < 8; ++ks) {
    U8 a;
    a.f4 = *(const float4*)&SL[lo16 * 264 + ks * 32 + kg * 8];
    acc = __builtin_amdgcn_mfma_f32_16x16x32_f16(a.v, bf[ks].v, acc, 0, 0, 0);
  }

  const float bias = (c < HID) ? b1[c] : 0.0f;
#pragma unroll
  for (int reg = 0; reg < 4; ++reg)
    P[(size_t)(row0 + kg * 4 + reg) * 256 + c] = (_Float16)(acc[reg] + bias);

  // W2T build (R0-validated): 16x128 f16, rows n>=8 zeroed.
  if (blockIdx.x == 0 && blockIdx.y == 0) {
#pragma unroll
    for (int p = 0; p < 8; ++p) {
      const int idx = threadIdx.x + p * 256;
      const int n = idx >> 7, k = idx & 127;
      W2T[n * 128 + k] = (n < 8) ? (_Float16)W2[k * NREL + n] : (_Float16)0.0f;
    }
  }
}

// pair (R20-identical except W2 frags come from W2T as 4x float4)
// out[b,i,j,r] = sigmoid( sum_k relu(P[b,i,k]+P[b,j,128+k]) * W2[k,r] + b2[r] )
__global__ __launch_bounds__(256) void pair_kernel(
    const _Float16* __restrict__ P, const _Float16* __restrict__ W2T,
    const float* __restrict__ b2, float* __restrict__ out) {
  __shared__ uint32_t PiL[8 * 68];

  const int tid  = threadIdx.x;
  const int w    = tid >> 6;
  const int lane = tid & 63;
  const int n    = lane & 15;
  const int kg   = lane >> 4;

  const int b  = blockIdx.z;
  const int i0 = blockIdx.y * 8;
  const int j0 = blockIdx.x * 64 + w * 16;
  const _Float16* Pb = P + (size_t)b * NSLOT * 256;

  if (tid < 128) {  // stage Pi: 8 rows x 128 f16
    const int r  = tid >> 4;
    const int ch = tid & 15;
    const float4 t = *(const float4*)(Pb + (size_t)(i0 + r) * 256 + ch * 8);
    *(float4*)&PiL[r * 68 + ch * 4] = t;
  }

  // W2 B-frags: 4x float4 from precomputed W2T (rows n>=8 are zeros)
  U8 w2f[4];
#pragma unroll
  for (int kq = 0; kq < 4; ++kq)
    w2f[kq].f4 = *(const float4*)(W2T + n * 128 + kq * 32 + kg * 8);

  const float b2v = (n < NREL) ? b2[n & 7] : 0.0f;

  U8 pj[4];
#pragma unroll
  for (int kq = 0; kq < 4; ++kq)
    pj[kq].f4 =
        *(const float4*)(Pb + (size_t)(j0 + n) * 256 + HID + kq * 32 + kg * 8);

  __syncthreads();

#pragma unroll
  for (int i = 0; i < 8; ++i) {
    float4v acc = {0.0f, 0.0f, 0.0f, 0.0f};
#pragma unroll
    for (int kq = 0; kq < 4; ++kq) {
      U8 pi;
      pi.f4 = *(const float4*)&PiL[i * 68 + kq * 16 + kg * 4];  // broadcast
      U8 h;
      h.v = __builtin_elementwise_max(pj[kq].v + pi.v, (half8)(_Float16)0.0f);
      acc = __builtin_amdgcn_mfma_f32_16x16x32_f16(h.v, w2f[kq].v, acc, 0, 0, 0);
    }
    if (n < NREL) {
      float* obase =
          out + (((size_t)b * NSLOT + (i0 + i)) * NSLOT + j0) * NREL + n;
#pragma unroll
      for (int reg = 0; reg < 4; ++reg) {
        const int jrow = kg * 4 + reg;
        const float x = acc[reg] + b2v;
        obase[jrow * NREL] = __builtin_amdgcn_rcpf(1.0f + __expf(-x));
      }
    }
  }
}

extern "C" void kernel_launch(void* const* d_in, const int* in_sizes, int n_in,
                              void* d_out, int out_size, void* d_ws,
                              size_t ws_size, hipStream_t stream) {
  const float* slots = (const float*)d_in[0];  // [8,256,256]
  const float* W1    = (const float*)d_in[1];  // [512,128]
  const float* b1    = (const float*)d_in[2];  // [128]
  const float* W2    = (const float*)d_in[3];  // [128,8]
  const float* b2    = (const float*)d_in[4];  // [8]
  float* out    = (float*)d_out;               // [8,256,256,8]
  _Float16* P   = (_Float16*)d_ws;                        // 1 MB
  _Float16* W2T = (_Float16*)((char*)d_ws + (1 << 20));   // 4 KB

  proj_kernel<<<dim3(4, 128), 256, 0, stream>>>(slots, W1, b1, W2, P, W2T);
  pair_kernel<<<dim3(NSLOT / 64, NSLOT / 8, BATCH), 256, 0, stream>>>(
      P, W2T, b2, out);
}